// Round 1
// baseline (189.038 us; speedup 1.0000x reference)
//
#include <hip/hip_runtime.h>
#include <cstdint>
#include <cstddef>

typedef unsigned short u16;
typedef __bf16 bf16x8 __attribute__((ext_vector_type(8)));
typedef float f32x4 __attribute__((ext_vector_type(4)));

#define AS1 __attribute__((address_space(1)))
#define AS3 __attribute__((address_space(3)))

__device__ __forceinline__ void gld16(const u16* g, u16* l) {
  __builtin_amdgcn_global_load_lds((const AS1 void*)(const void*)g,
                                   (AS3 void*)(void*)l, 16, 0, 0);
}

__device__ __forceinline__ u16 f2bf(float f) {
  union { float f; unsigned u; } x; x.f = f;
  return (u16)((x.u + 0x7fffu + ((x.u >> 16) & 1u)) >> 16);
}

// ---------- conversion: fp32 -> bf16 (vectorized) ----------
__global__ void k_cvt(const float* __restrict__ in, u16* __restrict__ out, int n4) {
  int i = blockIdx.x * blockDim.x + threadIdx.x;
  if (i >= n4) return;
  float4 v = reinterpret_cast<const float4*>(in)[i];
  ushort4 o;
  o.x = f2bf(v.x); o.y = f2bf(v.y); o.z = f2bf(v.z); o.w = f2bf(v.w);
  reinterpret_cast<ushort4*>(out)[i] = o;
}

// ---------- transpose 1024x1024 fp32 -> bf16, out[n][k] = in[k][n] ----------
__global__ void k_tr(const float* __restrict__ in, u16* __restrict__ out) {
  __shared__ float t[32][33];
  int bx = blockIdx.x * 32, by = blockIdx.y * 32;
  int tx = threadIdx.x, ty = threadIdx.y;  // (32, 8)
#pragma unroll
  for (int j = 0; j < 32; j += 8)
    t[ty + j][tx] = in[(size_t)(by + ty + j) * 1024 + bx + tx];
  __syncthreads();
#pragma unroll
  for (int j = 0; j < 32; j += 8)
    out[(size_t)(bx + ty + j) * 1024 + by + tx] = f2bf(t[tx][ty + j]);
}

// ---------- GEMM1: [4096 x 3072 x 1024], epilogue scatters Q(scaled)/K/V^T ----------
__global__ __launch_bounds__(256) void k_gemm_qkv(
    const u16* __restrict__ Xb,   // [4096][1024] bf16
    const u16* __restrict__ Wt,   // [3072][1024] bf16 (W^T, q|k|v stacked)
    u16* __restrict__ Qb,         // [B*H][2048][64], pre-scaled by 0.125
    u16* __restrict__ Kb,         // [B*H][2048][64]
    u16* __restrict__ Vt) {       // [B*H][64][2048]
  __shared__ __align__(16) u16 As[128][32];
  __shared__ __align__(16) u16 Bs[128][32];
  const int tid = threadIdx.x;
  const int w = tid >> 6, l = tid & 63;
  const int bm = blockIdx.x * 128;
  const int bn = blockIdx.y * 128;
  const int wm = (w >> 1) * 64, wn = (w & 1) * 64;
  const int lm = l & 15, lg = l >> 4;

  f32x4 acc[4][4];
#pragma unroll
  for (int i = 0; i < 4; ++i)
#pragma unroll
    for (int j = 0; j < 4; ++j) acc[i][j] = f32x4{0.f, 0.f, 0.f, 0.f};

  const int srow = w * 16 + (l >> 2);   // 4 lanes/row, 16 rows per wave-issue
  const int scol = (l & 3) * 8;
  for (int k0 = 0; k0 < 1024; k0 += 32) {
#pragma unroll
    for (int j = 0; j < 2; ++j) {
      gld16(Xb + (size_t)(bm + j * 64 + srow) * 1024 + k0 + scol, &As[j * 64 + w * 16][0]);
      gld16(Wt + (size_t)(bn + j * 64 + srow) * 1024 + k0 + scol, &Bs[j * 64 + w * 16][0]);
    }
    __syncthreads();
    bf16x8 af[4], bfr[4];
#pragma unroll
    for (int mt = 0; mt < 4; ++mt)
      af[mt] = *reinterpret_cast<const bf16x8*>(&As[wm + mt * 16 + lm][lg * 8]);
#pragma unroll
    for (int nt = 0; nt < 4; ++nt)
      bfr[nt] = *reinterpret_cast<const bf16x8*>(&Bs[wn + nt * 16 + lm][lg * 8]);
#pragma unroll
    for (int mt = 0; mt < 4; ++mt)
#pragma unroll
      for (int nt = 0; nt < 4; ++nt)
        acc[mt][nt] = __builtin_amdgcn_mfma_f32_16x16x32_bf16(af[mt], bfr[nt], acc[mt][nt], 0, 0, 0);
    __syncthreads();
  }
  // epilogue: C/D layout col=lane&15, row=(lane>>4)*4+reg
#pragma unroll
  for (int nt = 0; nt < 4; ++nt) {
    int gc = bn + wn + nt * 16 + lm;
    int which = gc >> 10, jc = gc & 1023, h = jc >> 6, d = jc & 63;
#pragma unroll
    for (int mt = 0; mt < 4; ++mt) {
#pragma unroll
      for (int r = 0; r < 4; ++r) {
        int gr = bm + wm + mt * 16 + lg * 4 + r;
        int b = gr >> 11, s = gr & 2047;
        float v = acc[mt][nt][r];
        size_t bh = (size_t)(b * 16 + h);
        if (which == 0)      Qb[(bh * 2048 + s) * 64 + d] = f2bf(v * 0.125f);
        else if (which == 1) Kb[(bh * 2048 + s) * 64 + d] = f2bf(v);
        else                 Vt[(bh * 64 + d) * 2048 + s] = f2bf(v);
      }
    }
  }
}

// ---------- flash attention: grid (32 qtiles, 32 bh), 4 waves x 16 q-rows ----------
__global__ __launch_bounds__(256) void k_attn(
    const u16* __restrict__ Qb, const u16* __restrict__ Kb,
    const u16* __restrict__ Vt, u16* __restrict__ Ob) {  // Ob: [4096][1024] bf16
  __shared__ __align__(16) u16 Ks[64][64];      // [kv][dk], XOR-swizzled chunks
  __shared__ __align__(16) u16 Vs[64][64];      // [d][kv],  XOR-swizzled chunks
  __shared__ __align__(16) u16 Ps[4][16][72];   // per-wave P, padded rows
  const int tid = threadIdx.x, w = tid >> 6, l = tid & 63;
  const int lm = l & 15, lg = l >> 4;
  const int bh = blockIdx.y;
  const int q0 = blockIdx.x * 64 + w * 16;
  const u16* Qh = Qb + (size_t)bh * 2048 * 64;
  const u16* Kh = Kb + (size_t)bh * 2048 * 64;
  const u16* Vh = Vt + (size_t)bh * 64 * 2048;

  bf16x8 qf0 = *reinterpret_cast<const bf16x8*>(&Qh[(size_t)(q0 + lm) * 64 + lg * 8]);
  bf16x8 qf1 = *reinterpret_cast<const bf16x8*>(&Qh[(size_t)(q0 + lm) * 64 + 32 + lg * 8]);

  float mrow[4], lrow[4];
  f32x4 oacc[4];
#pragma unroll
  for (int r = 0; r < 4; ++r) { mrow[r] = -1e30f; lrow[r] = 0.f; }
#pragma unroll
  for (int nt = 0; nt < 4; ++nt) oacc[nt] = f32x4{0.f, 0.f, 0.f, 0.f};

  const int srow = w * 8 + (l >> 3);                 // 8 lanes/row
  const int schunk = (l & 7) ^ ((l >> 3) & 7);       // inverse-swizzled source chunk

  for (int kv0 = 0; kv0 < 2048; kv0 += 64) {
#pragma unroll
    for (int j = 0; j < 2; ++j) {
      int r = j * 32 + srow;
      gld16(Kh + (size_t)(kv0 + r) * 64 + schunk * 8, &Ks[j * 32 + w * 8][0]);
      gld16(Vh + (size_t)r * 2048 + kv0 + schunk * 8, &Vs[j * 32 + w * 8][0]);
    }
    __syncthreads();

    // S = Q K^T  (Q pre-scaled by 0.125)
    f32x4 st[4];
#pragma unroll
    for (int t = 0; t < 4; ++t) {
      int row = t * 16 + lm;
      const u16* kr = &Ks[row][0];
      bf16x8 kf0 = *reinterpret_cast<const bf16x8*>(kr + (((lg)     ^ (row & 7)) << 3));
      bf16x8 kf1 = *reinterpret_cast<const bf16x8*>(kr + (((lg + 4) ^ (row & 7)) << 3));
      f32x4 z = f32x4{0.f, 0.f, 0.f, 0.f};
      z = __builtin_amdgcn_mfma_f32_16x16x32_bf16(qf0, kf0, z, 0, 0, 0);
      st[t] = __builtin_amdgcn_mfma_f32_16x16x32_bf16(qf1, kf1, z, 0, 0, 0);
    }

    // online softmax (rows spread over 16 lanes)
    float sc[4], ps[4];
#pragma unroll
    for (int r = 0; r < 4; ++r) {
      float mx = fmaxf(fmaxf(st[0][r], st[1][r]), fmaxf(st[2][r], st[3][r]));
      mx = fmaxf(mx, __shfl_xor(mx, 1));
      mx = fmaxf(mx, __shfl_xor(mx, 2));
      mx = fmaxf(mx, __shfl_xor(mx, 4));
      mx = fmaxf(mx, __shfl_xor(mx, 8));
      float mnew = fmaxf(mrow[r], mx);
      sc[r] = __expf(mrow[r] - mnew);
      mrow[r] = mnew;
      ps[r] = 0.f;
    }
#pragma unroll
    for (int t = 0; t < 4; ++t) {
#pragma unroll
      for (int r = 0; r < 4; ++r) {
        float p = __expf(st[t][r] - mrow[r]);
        ps[r] += p;
        Ps[w][lg * 4 + r][t * 16 + lm] = f2bf(p);
      }
    }
#pragma unroll
    for (int r = 0; r < 4; ++r) {
      float s = ps[r];
      s += __shfl_xor(s, 1); s += __shfl_xor(s, 2);
      s += __shfl_xor(s, 4); s += __shfl_xor(s, 8);
      lrow[r] = lrow[r] * sc[r] + s;
    }
#pragma unroll
    for (int nt = 0; nt < 4; ++nt)
#pragma unroll
      for (int r = 0; r < 4; ++r) oacc[nt][r] *= sc[r];

    // O += P V   (A from per-wave Ps, B from swizzled Vs)
    bf16x8 pa0 = *reinterpret_cast<const bf16x8*>(&Ps[w][lm][lg * 8]);
    bf16x8 pa1 = *reinterpret_cast<const bf16x8*>(&Ps[w][lm][32 + lg * 8]);
#pragma unroll
    for (int nt = 0; nt < 4; ++nt) {
      int row = nt * 16 + lm;
      const u16* vr = &Vs[row][0];
      bf16x8 vf0 = *reinterpret_cast<const bf16x8*>(vr + (((lg)     ^ (row & 7)) << 3));
      bf16x8 vf1 = *reinterpret_cast<const bf16x8*>(vr + (((lg + 4) ^ (row & 7)) << 3));
      oacc[nt] = __builtin_amdgcn_mfma_f32_16x16x32_bf16(pa0, vf0, oacc[nt], 0, 0, 0);
      oacc[nt] = __builtin_amdgcn_mfma_f32_16x16x32_bf16(pa1, vf1, oacc[nt], 0, 0, 0);
    }
    __syncthreads();
  }

  const int b = bh >> 4, h = bh & 15;
#pragma unroll
  for (int nt = 0; nt < 4; ++nt) {
    int d = nt * 16 + lm;
#pragma unroll
    for (int r = 0; r < 4; ++r) {
      int q = q0 + lg * 4 + r;
      float o = oacc[nt][r] / lrow[r];
      Ob[((size_t)b * 2048 + q) * 1024 + h * 64 + d] = f2bf(o);
    }
  }
}

// ---------- GEMM2: [4096 x 1024 x 1024] + bias, fp32 out ----------
__global__ __launch_bounds__(256) void k_gemm_out(
    const u16* __restrict__ Ab,   // [4096][1024] bf16
    const u16* __restrict__ Wot,  // [1024][1024] bf16 (Wo^T)
    const float* __restrict__ bias, float* __restrict__ out) {
  __shared__ __align__(16) u16 As[128][32];
  __shared__ __align__(16) u16 Bs[128][32];
  const int tid = threadIdx.x;
  const int w = tid >> 6, l = tid & 63;
  const int bm = blockIdx.x * 128;
  const int bn = blockIdx.y * 128;
  const int wm = (w >> 1) * 64, wn = (w & 1) * 64;
  const int lm = l & 15, lg = l >> 4;

  f32x4 acc[4][4];
#pragma unroll
  for (int i = 0; i < 4; ++i)
#pragma unroll
    for (int j = 0; j < 4; ++j) acc[i][j] = f32x4{0.f, 0.f, 0.f, 0.f};

  const int srow = w * 16 + (l >> 2);
  const int scol = (l & 3) * 8;
  for (int k0 = 0; k0 < 1024; k0 += 32) {
#pragma unroll
    for (int j = 0; j < 2; ++j) {
      gld16(Ab  + (size_t)(bm + j * 64 + srow) * 1024 + k0 + scol, &As[j * 64 + w * 16][0]);
      gld16(Wot + (size_t)(bn + j * 64 + srow) * 1024 + k0 + scol, &Bs[j * 64 + w * 16][0]);
    }
    __syncthreads();
    bf16x8 af[4], bfr[4];
#pragma unroll
    for (int mt = 0; mt < 4; ++mt)
      af[mt] = *reinterpret_cast<const bf16x8*>(&As[wm + mt * 16 + lm][lg * 8]);
#pragma unroll
    for (int nt = 0; nt < 4; ++nt)
      bfr[nt] = *reinterpret_cast<const bf16x8*>(&Bs[wn + nt * 16 + lm][lg * 8]);
#pragma unroll
    for (int mt = 0; mt < 4; ++mt)
#pragma unroll
      for (int nt = 0; nt < 4; ++nt)
        acc[mt][nt] = __builtin_amdgcn_mfma_f32_16x16x32_bf16(af[mt], bfr[nt], acc[mt][nt], 0, 0, 0);
    __syncthreads();
  }
#pragma unroll
  for (int nt = 0; nt < 4; ++nt) {
    int gc = bn + wn + nt * 16 + lm;
    float bv = bias[gc];
#pragma unroll
    for (int mt = 0; mt < 4; ++mt) {
#pragma unroll
      for (int r = 0; r < 4; ++r) {
        int gr = bm + wm + mt * 16 + lg * 4 + r;
        out[(size_t)gr * 1024 + gc] = acc[mt][nt][r] + bv;
      }
    }
  }
}

extern "C" void kernel_launch(void* const* d_in, const int* in_sizes, int n_in,
                              void* d_out, int out_size, void* d_ws, size_t ws_size,
                              hipStream_t stream) {
  const float* X  = (const float*)d_in[0];
  const float* wq = (const float*)d_in[1];
  const float* wk = (const float*)d_in[2];
  const float* wv = (const float*)d_in[3];
  const float* wo = (const float*)d_in[4];
  const float* bo = (const float*)d_in[5];
  float* out = (float*)d_out;

  char* ws = (char*)d_ws;
  u16* Xb   = (u16*)(ws);                        // 8 MB  [0,8M)
  u16* Wqkv = (u16*)(ws + (size_t)(8u  << 20));  // 6 MB  [8,14M)
  u16* Wot  = (u16*)(ws + (size_t)(14u << 20));  // 2 MB  [14,16M)
  u16* Qb   = (u16*)(ws + (size_t)(16u << 20));  // 8 MB
  u16* Kb   = (u16*)(ws + (size_t)(24u << 20));  // 8 MB
  u16* Vt   = (u16*)(ws + (size_t)(32u << 20));  // 8 MB
  u16* Ab   = (u16*)(ws + (size_t)(40u << 20));  // 8 MB  -> total 48 MB

  k_cvt<<<4096, 256, 0, stream>>>(X, Xb, 4096 * 1024 / 4);
  dim3 trb(32, 8), trg(32, 32);
  k_tr<<<trg, trb, 0, stream>>>(wq, Wqkv);
  k_tr<<<trg, trb, 0, stream>>>(wk, Wqkv + (size_t)(1u << 20));
  k_tr<<<trg, trb, 0, stream>>>(wv, Wqkv + (size_t)(2u << 20));
  k_tr<<<trg, trb, 0, stream>>>(wo, Wot);
  k_gemm_qkv<<<dim3(32, 24), 256, 0, stream>>>(Xb, Wqkv, Qb, Kb, Vt);
  k_attn<<<dim3(32, 32), 256, 0, stream>>>(Qb, Kb, Vt, Ab);
  k_gemm_out<<<dim3(32, 8), 256, 0, stream>>>(Ab, Wot, bo, out);
}

// Round 2
// 147.297 us; speedup vs baseline: 1.2834x; 1.2834x over previous
//
#include <hip/hip_runtime.h>
#include <cstdint>
#include <cstddef>

typedef unsigned short u16;
typedef unsigned int u32;
typedef __bf16 bf16x8 __attribute__((ext_vector_type(8)));
typedef float f32x4 __attribute__((ext_vector_type(4)));
typedef float f32x16 __attribute__((ext_vector_type(16)));
typedef u32 u32x2 __attribute__((ext_vector_type(2)));
typedef u32 u32x4 __attribute__((ext_vector_type(4)));

#define AS1 __attribute__((address_space(1)))
#define AS3 __attribute__((address_space(3)))

__device__ __forceinline__ void gld16(const u16* g, u16* l) {
  __builtin_amdgcn_global_load_lds((const AS1 void*)(const void*)g,
                                   (AS3 void*)(void*)l, 16, 0, 0);
}

__device__ __forceinline__ u16 f2bf(float f) {
  union { float f; unsigned u; } x; x.f = f;
  return (u16)((x.u + 0x7fffu + ((x.u >> 16) & 1u)) >> 16);
}

__device__ __forceinline__ f32x16 zf16() {
  f32x16 v;
#pragma unroll
  for (int i = 0; i < 16; ++i) v[i] = 0.f;
  return v;
}

// ---------- conversion: fp32 -> bf16 (vectorized) ----------
__global__ void k_cvt(const float* __restrict__ in, u16* __restrict__ out, int n4) {
  int i = blockIdx.x * blockDim.x + threadIdx.x;
  if (i >= n4) return;
  float4 v = reinterpret_cast<const float4*>(in)[i];
  ushort4 o;
  o.x = f2bf(v.x); o.y = f2bf(v.y); o.z = f2bf(v.z); o.w = f2bf(v.w);
  reinterpret_cast<ushort4*>(out)[i] = o;
}

// ---------- transpose 1024x1024 fp32 -> bf16, out[n][k] = in[k][n] ----------
__global__ void k_tr(const float* __restrict__ in, u16* __restrict__ out) {
  __shared__ float t[32][33];
  int bx = blockIdx.x * 32, by = blockIdx.y * 32;
  int tx = threadIdx.x, ty = threadIdx.y;  // (32, 8)
#pragma unroll
  for (int j = 0; j < 32; j += 8)
    t[ty + j][tx] = in[(size_t)(by + ty + j) * 1024 + bx + tx];
  __syncthreads();
#pragma unroll
  for (int j = 0; j < 32; j += 8)
    out[(size_t)(bx + ty + j) * 1024 + by + tx] = f2bf(t[tx][ty + j]);
}

// ---------- GEMM1: [4096 x 3072 x 1024], epilogue scatters Q(scaled)/K/V^T ----------
// Q pre-scaled by DIM_HEAD^-0.5 * log2(e) so attention softmax runs in exp2 domain.
__global__ __launch_bounds__(256) void k_gemm_qkv(
    const u16* __restrict__ Xb,   // [4096][1024] bf16
    const u16* __restrict__ Wt,   // [3072][1024] bf16 (W^T, q|k|v stacked)
    u16* __restrict__ Qb,         // [B*H][2048][64], pre-scaled
    u16* __restrict__ Kb,         // [B*H][2048][64]
    u16* __restrict__ Vt) {       // [B*H][64][2048]
  __shared__ __align__(16) u16 As[128][32];
  __shared__ __align__(16) u16 Bs[128][32];
  const int tid = threadIdx.x;
  const int w = tid >> 6, l = tid & 63;
  const int bm = blockIdx.x * 128;
  const int bn = blockIdx.y * 128;
  const int wm = (w >> 1) * 64, wn = (w & 1) * 64;
  const int lm = l & 15, lg = l >> 4;

  f32x4 acc[4][4];
#pragma unroll
  for (int i = 0; i < 4; ++i)
#pragma unroll
    for (int j = 0; j < 4; ++j) acc[i][j] = f32x4{0.f, 0.f, 0.f, 0.f};

  const int srow = w * 16 + (l >> 2);   // 4 lanes/row, 16 rows per wave-issue
  const int scol = (l & 3) * 8;
  for (int k0 = 0; k0 < 1024; k0 += 32) {
#pragma unroll
    for (int j = 0; j < 2; ++j) {
      gld16(Xb + (size_t)(bm + j * 64 + srow) * 1024 + k0 + scol, &As[j * 64 + w * 16][0]);
      gld16(Wt + (size_t)(bn + j * 64 + srow) * 1024 + k0 + scol, &Bs[j * 64 + w * 16][0]);
    }
    __syncthreads();
    bf16x8 af[4], bfr[4];
#pragma unroll
    for (int mt = 0; mt < 4; ++mt)
      af[mt] = *reinterpret_cast<const bf16x8*>(&As[wm + mt * 16 + lm][lg * 8]);
#pragma unroll
    for (int nt = 0; nt < 4; ++nt)
      bfr[nt] = *reinterpret_cast<const bf16x8*>(&Bs[wn + nt * 16 + lm][lg * 8]);
#pragma unroll
    for (int mt = 0; mt < 4; ++mt)
#pragma unroll
      for (int nt = 0; nt < 4; ++nt)
        acc[mt][nt] = __builtin_amdgcn_mfma_f32_16x16x32_bf16(af[mt], bfr[nt], acc[mt][nt], 0, 0, 0);
    __syncthreads();
  }
  // epilogue: C/D layout col=lane&15, row=(lane>>4)*4+reg
#pragma unroll
  for (int nt = 0; nt < 4; ++nt) {
    int gc = bn + wn + nt * 16 + lm;
    int which = gc >> 10, jc = gc & 1023, h = jc >> 6, d = jc & 63;
#pragma unroll
    for (int mt = 0; mt < 4; ++mt) {
#pragma unroll
      for (int r = 0; r < 4; ++r) {
        int gr = bm + wm + mt * 16 + lg * 4 + r;
        int b = gr >> 11, s = gr & 2047;
        float v = acc[mt][nt][r];
        size_t bh = (size_t)(b * 16 + h);
        if (which == 0)      Qb[(bh * 2048 + s) * 64 + d] = f2bf(v * 0.18033688f);
        else if (which == 1) Kb[(bh * 2048 + s) * 64 + d] = f2bf(v);
        else                 Vt[(bh * 64 + d) * 2048 + s] = f2bf(v);
      }
    }
  }
}

// ---------- flash attention, swapped-QK^T 32x32 structure ----------
// Grid (16 q-blocks, 32 bh), 4 waves x 32 q-rows. Per lane: q = q0 + (lane&31).
// S^T tile = mfma(A=K, B=Q) -> D[kv][q]: lane holds 32 scores of ONE q-row in regs.
// PV: A = P directly (V B-frag kv-order chosen to match P's natural crow layout).
__global__ __launch_bounds__(256) void k_attn(
    const u16* __restrict__ Qb, const u16* __restrict__ Kb,
    const u16* __restrict__ Vt, u16* __restrict__ Ob) {  // Ob: [4096][1024] bf16
  __shared__ __align__(16) u16 Ks[2][64][64];   // [buf][kv][d], 16B-granule XOR row&7
  __shared__ __align__(16) u16 Vs[2][64][64];   // [buf][d][pos], pos = kv bit2<->bit3, XOR row&7
  __shared__ float scb[4][32];
  __shared__ float lb[4][32];
  const int tid = threadIdx.x, w = tid >> 6, l = tid & 63;
  const int lm = l & 31, hi = l >> 5;
  const int kx = lm & 7;
  const int bh = blockIdx.y;
  const int q0 = blockIdx.x * 128 + w * 32;
  const u16* Qh = Qb + (size_t)bh * 2048 * 64;
  const u16* Kh = Kb + (size_t)bh * 2048 * 64;
  const u16* Vh = Vt + (size_t)bh * 64 * 2048;

  // Q fragments (held whole kernel): q = q0+lm, slot (c,hi,i) -> d = 16c+8hi+i
  bf16x8 qf[4];
#pragma unroll
  for (int c = 0; c < 4; ++c)
    qf[c] = *reinterpret_cast<const bf16x8*>(&Qh[(size_t)(q0 + lm) * 64 + 16 * c + 8 * hi]);

  f32x16 oacc0 = zf16(), oacc1 = zf16();
  float m = -1e30f, lsum = 0.f;

  const int r4 = l >> 2;                 // V-stage row within wave's 16
  const int vrow = w * 16 + r4;          // V-stage LDS row (= d)

  // ---- prologue: stage tile 0 into buf 0
  {
    u32x2 vreg[2][2];
#pragma unroll
    for (int ch = 0; ch < 2; ++ch) {
      int pg = ((l & 3) + 4 * ch + r4) & 7;          // physical 16B granule
      int g = pg ^ (r4 & 7);                         // logical granule
      int base = ((g >> 1) << 4) | ((g & 1) << 2);   // kv base of content
      const u16* src = Vh + (size_t)vrow * 2048 + base;
      vreg[ch][0] = *reinterpret_cast<const u32x2*>(src);
      vreg[ch][1] = *reinterpret_cast<const u32x2*>(src + 8);
    }
#pragma unroll
    for (int j = 0; j < 2; ++j) {
      int row = w * 16 + j * 8 + (l >> 3);
      int g = (l & 7) ^ (row & 7);
      gld16(Kh + (size_t)row * 64 + 8 * g, &Ks[0][w * 16 + j * 8][0]);
    }
#pragma unroll
    for (int ch = 0; ch < 2; ++ch) {
      int pg = ((l & 3) + 4 * ch + r4) & 7;
      u32x4 pk;
      pk[0] = vreg[ch][0][0]; pk[1] = vreg[ch][0][1];
      pk[2] = vreg[ch][1][0]; pk[3] = vreg[ch][1][1];
      *reinterpret_cast<u32x4*>(&Vs[0][vrow][pg * 8]) = pk;
    }
  }
  __syncthreads();

  for (int t = 0; t < 32; ++t) {
    const int cur = t & 1, nxt = cur ^ 1;
    const int kvn = (t + 1) * 64;
    u32x2 vreg[2][2];
    if (t < 31) {
      // T14: issue next tile's V global loads early; K via async global_load_lds
#pragma unroll
      for (int ch = 0; ch < 2; ++ch) {
        int pg = ((l & 3) + 4 * ch + r4) & 7;
        int g = pg ^ (r4 & 7);
        int base = ((g >> 1) << 4) | ((g & 1) << 2);
        const u16* src = Vh + (size_t)vrow * 2048 + kvn + base;
        vreg[ch][0] = *reinterpret_cast<const u32x2*>(src);
        vreg[ch][1] = *reinterpret_cast<const u32x2*>(src + 8);
      }
#pragma unroll
      for (int j = 0; j < 2; ++j) {
        int row = w * 16 + j * 8 + (l >> 3);
        int g = (l & 7) ^ (row & 7);
        gld16(Kh + (size_t)(kvn + row) * 64 + 8 * g, &Ks[nxt][w * 16 + j * 8][0]);
      }
    }

    // ---- S^T = K Q^T (both tiles), D[kv][q]: lane q = lm, kv = crow(r,hi)+32t
    const u16* Kc = &Ks[cur][0][0];
    f32x16 st0 = zf16(), st1 = zf16();
#pragma unroll
    for (int c = 0; c < 4; ++c) {
      bf16x8 kf0 = *reinterpret_cast<const bf16x8*>(Kc + (size_t)lm * 64 + 8 * ((2 * c + hi) ^ kx));
      st0 = __builtin_amdgcn_mfma_f32_32x32x16_bf16(kf0, qf[c], st0, 0, 0, 0);
    }
#pragma unroll
    for (int c = 0; c < 4; ++c) {
      bf16x8 kf1 = *reinterpret_cast<const bf16x8*>(Kc + (size_t)(32 + lm) * 64 + 8 * ((2 * c + hi) ^ kx));
      st1 = __builtin_amdgcn_mfma_f32_32x32x16_bf16(kf1, qf[c], st1, 0, 0, 0);
    }

    // ---- online softmax (log2 domain), defer-max THR=8
    float tm = st0[0];
#pragma unroll
    for (int r = 1; r < 16; ++r) tm = fmaxf(tm, st0[r]);
#pragma unroll
    for (int r = 0; r < 16; ++r) tm = fmaxf(tm, st1[r]);
    tm = fmaxf(tm, __shfl_xor(tm, 32));
    if (!__all(tm - m <= 8.0f)) {
      float mnew = fmaxf(m, tm);
      scb[w][lm] = exp2f(m - mnew);
      asm volatile("s_waitcnt lgkmcnt(0)" ::: "memory");
      __builtin_amdgcn_sched_barrier(0);
      lsum *= exp2f(m - mnew);
#pragma unroll
      for (int r = 0; r < 16; ++r) {
        int cr = (r & 3) + 8 * (r >> 2) + 4 * hi;
        float s = scb[w][cr];
        oacc0[r] *= s; oacc1[r] *= s;
      }
      m = mnew;
    }
    float ps = 0.f;
    bf16x8 pf[2][2];
#pragma unroll
    for (int j = 0; j < 2; ++j)
#pragma unroll
      for (int ii = 0; ii < 8; ++ii) {
        float p0 = exp2f(st0[8 * j + ii] - m);
        float p1 = exp2f(st1[8 * j + ii] - m);
        ps += p0 + p1;
        pf[0][j][ii] = (__bf16)p0;
        pf[1][j][ii] = (__bf16)p1;
      }
    ps += __shfl_xor(ps, 32);
    lsum += ps;

    // ---- O += P V  (A = pf directly; B from Vs pos-layout)
    const u16* Vc = &Vs[cur][0][0];
#pragma unroll
    for (int tt = 0; tt < 2; ++tt)
#pragma unroll
      for (int j = 0; j < 2; ++j) {
        int gA = (4 * tt + 2 * j + hi) ^ kx;
        bf16x8 v0 = *reinterpret_cast<const bf16x8*>(Vc + (size_t)lm * 64 + 8 * gA);
        bf16x8 v1 = *reinterpret_cast<const bf16x8*>(Vc + (size_t)(32 + lm) * 64 + 8 * gA);
        oacc0 = __builtin_amdgcn_mfma_f32_32x32x16_bf16(pf[tt][j], v0, oacc0, 0, 0, 0);
        oacc1 = __builtin_amdgcn_mfma_f32_32x32x16_bf16(pf[tt][j], v1, oacc1, 0, 0, 0);
      }

    if (t < 31) {
      // T14: LDS write of next V after compute (vmcnt covered by compute phase)
#pragma unroll
      for (int ch = 0; ch < 2; ++ch) {
        int pg = ((l & 3) + 4 * ch + r4) & 7;
        u32x4 pk;
        pk[0] = vreg[ch][0][0]; pk[1] = vreg[ch][0][1];
        pk[2] = vreg[ch][1][0]; pk[3] = vreg[ch][1][1];
        *reinterpret_cast<u32x4*>(&Vs[nxt][vrow][pg * 8]) = pk;
      }
    }
    __syncthreads();
  }

  // ---- epilogue: per-row l broadcast (wave-local LDS), normalize, store
  lb[w][lm] = lsum;
  asm volatile("s_waitcnt lgkmcnt(0)" ::: "memory");
  __builtin_amdgcn_sched_barrier(0);
  const int b = bh >> 4, h = bh & 15;
#pragma unroll
  for (int r = 0; r < 16; ++r) {
    int cr = (r & 3) + 8 * (r >> 2) + 4 * hi;
    float inv = 1.0f / lb[w][cr];
    size_t ro = ((size_t)(b * 2048 + q0 + cr)) * 1024 + h * 64;
    Ob[ro + lm]      = f2bf(oacc0[r] * inv);
    Ob[ro + 32 + lm] = f2bf(oacc1[r] * inv);
  }
}

// ---------- GEMM2: [4096 x 1024 x 1024] + bias, fp32 out ----------
__global__ __launch_bounds__(256) void k_gemm_out(
    const u16* __restrict__ Ab,   // [4096][1024] bf16
    const u16* __restrict__ Wot,  // [1024][1024] bf16 (Wo^T)
    const float* __restrict__ bias, float* __restrict__ out) {
  __shared__ __align__(16) u16 As[128][32];
  __shared__ __align__(16) u16 Bs[128][32];
  const int tid = threadIdx.x;
  const int w = tid >> 6, l = tid & 63;
  const int bm = blockIdx.x * 128;
  const int bn = blockIdx.y * 128;
  const int wm = (w >> 1) * 64, wn = (w & 1) * 64;
  const int lm = l & 15, lg = l >> 4;

  f32x4 acc[4][4];
#pragma unroll
  for (int i = 0; i < 4; ++i)
#pragma unroll
    for (int j = 0; j < 4; ++j) acc[i][j] = f32x4{0.f, 0.f, 0.f, 0.f};

  const int srow = w * 16 + (l >> 2);
  const int scol = (l & 3) * 8;
  for (int k0 = 0; k0 < 1024; k0 += 32) {
#pragma unroll
    for (int j = 0; j < 2; ++j) {
      gld16(Ab  + (size_t)(bm + j * 64 + srow) * 1024 + k0 + scol, &As[j * 64 + w * 16][0]);
      gld16(Wot + (size_t)(bn + j * 64 + srow) * 1024 + k0 + scol, &Bs[j * 64 + w * 16][0]);
    }
    __syncthreads();
    bf16x8 af[4], bfr[4];
#pragma unroll
    for (int mt = 0; mt < 4; ++mt)
      af[mt] = *reinterpret_cast<const bf16x8*>(&As[wm + mt * 16 + lm][lg * 8]);
#pragma unroll
    for (int nt = 0; nt < 4; ++nt)
      bfr[nt] = *reinterpret_cast<const bf16x8*>(&Bs[wn + nt * 16 + lm][lg * 8]);
#pragma unroll
    for (int mt = 0; mt < 4; ++mt)
#pragma unroll
      for (int nt = 0; nt < 4; ++nt)
        acc[mt][nt] = __builtin_amdgcn_mfma_f32_16x16x32_bf16(af[mt], bfr[nt], acc[mt][nt], 0, 0, 0);
    __syncthreads();
  }
#pragma unroll
  for (int nt = 0; nt < 4; ++nt) {
    int gc = bn + wn + nt * 16 + lm;
    float bv = bias[gc];
#pragma unroll
    for (int mt = 0; mt < 4; ++mt) {
#pragma unroll
      for (int r = 0; r < 4; ++r) {
        int gr = bm + wm + mt * 16 + lg * 4 + r;
        out[(size_t)gr * 1024 + gc] = acc[mt][nt][r] + bv;
      }
    }
  }
}

extern "C" void kernel_launch(void* const* d_in, const int* in_sizes, int n_in,
                              void* d_out, int out_size, void* d_ws, size_t ws_size,
                              hipStream_t stream) {
  const float* X  = (const float*)d_in[0];
  const float* wq = (const float*)d_in[1];
  const float* wk = (const float*)d_in[2];
  const float* wv = (const float*)d_in[3];
  const float* wo = (const float*)d_in[4];
  const float* bo = (const float*)d_in[5];
  float* out = (float*)d_out;

  char* ws = (char*)d_ws;
  u16* Xb   = (u16*)(ws);                        // 8 MB  [0,8M)
  u16* Wqkv = (u16*)(ws + (size_t)(8u  << 20));  // 6 MB  [8,14M)
  u16* Wot  = (u16*)(ws + (size_t)(14u << 20));  // 2 MB  [14,16M)
  u16* Qb   = (u16*)(ws + (size_t)(16u << 20));  // 8 MB
  u16* Kb   = (u16*)(ws + (size_t)(24u << 20));  // 8 MB
  u16* Vt   = (u16*)(ws + (size_t)(32u << 20));  // 8 MB
  u16* Ab   = (u16*)(ws + (size_t)(40u << 20));  // 8 MB  -> total 48 MB

  k_cvt<<<4096, 256, 0, stream>>>(X, Xb, 4096 * 1024 / 4);
  dim3 trb(32, 8), trg(32, 32);
  k_tr<<<trg, trb, 0, stream>>>(wq, Wqkv);
  k_tr<<<trg, trb, 0, stream>>>(wk, Wqkv + (size_t)(1u << 20));
  k_tr<<<trg, trb, 0, stream>>>(wv, Wqkv + (size_t)(2u << 20));
  k_tr<<<trg, trb, 0, stream>>>(wo, Wot);
  k_gemm_qkv<<<dim3(32, 24), 256, 0, stream>>>(Xb, Wqkv, Qb, Kb, Vt);
  k_attn<<<dim3(16, 32), 256, 0, stream>>>(Qb, Kb, Vt, Ab);
  k_gemm_out<<<dim3(32, 8), 256, 0, stream>>>(Ab, Wot, bo, out);
}